// Round 16
// baseline (8650.298 us; speedup 1.0000x reference)
//
#include <hip/hip_runtime.h>
#include <math.h>

#define Bsz  128
#define Lseq 256
#define Hdim 512
#define G4   2048
#define NWG  256
#define NT   512
#define RB   32      // batch rows per wg
#define LHP  544     // row stride (dwords): 8 regions x 68
#define OUTHALF (Bsz * Lseq * 2)   // 65536: planar split re | im

// Bijective bank swizzle: linear dword d (0..511) -> stored dword (0..543).
// Region (64 dwords) gets 68 dwords of space; upper half of each region
// shifts +4 so the 8-dword lane chunks' addresses cover all 8 quad-bank
// slots (wave64 ds_read_b128 at its 8-phase floor). Images: [0,32)->[0,32),
// [32,64)->[36,68), region stride 68 -> disjoint, chunk-contiguous.
#define SWZ(d) (68 * ((d) >> 6) + ((d) & 63) + 4 * (((d) >> 5) & 1))

#define LH_ELEMS   (RB * LHP)                 // 17408
#define ZRED_ELEMS (2 * RB * 33)              // 2112: [lyz][row][col(33)]
#define MLP_ELEMS  80
#define LDS_FLOATS (2 * LH_ELEMS + ZRED_ELEMS + MLP_ELEMS)  // 37008
#define LDS_BYTES  (LDS_FLOATS * 4)           // 148,032 B < 160 KiB -> 1 wg/CU

struct PArgs {
  const float *x, *Wx0, *Wh0, *b0, *Wx1, *Wh1, *b1;   // original layouts [K][4H]
  const float *Wr1, *br1, *Wr2, *br2, *Wi1, *bi1, *Wi2, *bi2;
  float *H0, *H1;                             // double-buffered [2][128][512]
  int   *cnt;                                 // 8 barrier counters (monotonic)
  float *out;                                 // f32 PLANAR: [re (B,L,2)][im (B,L,2)]
};

__device__ __forceinline__ float sigf(float z) {
  return 1.f / (1.f + expf(-z));
}

__global__ void __launch_bounds__(NT, 1) lstm_persist(PArgs A) {
  const int w    = blockIdx.x;
  const int tid  = threadIdx.x;
  // XCD-aware mapping: XCD x hosts cs in [8x,8x+8) -> contiguous cols per L2.
  const int cs   = (w & 7) * 8 + ((w >> 3) & 7);  // 0..63
  const int bg   = w >> 6;                         // 0..3
  const int r0   = bg * RB;
  const int c0   = cs * 8;
  // GEMM: wave q = col-quad (4 gate-cols), lane owns k in [lane*8, lane*8+8)
  const int q    = tid >> 6;            // 0..7
  const int lane = tid & 63;
  const int kb   = lane << 3;
  const int koff = SWZ(kb);             // swizzled, chunk-contiguous base
  const int gq   = (q >> 1) * Hdim + c0 + (q & 1) * 4;
  // cell mapping (tid < 256): (row rr2, h-col hcc)
  const int rr2  = (tid >> 3) & 31;
  const int hcc  = tid & 7;
  // MLP mapping (tid < 256)
  const int wv   = (tid >> 6) & 3;

  extern __shared__ float lds[];
  float* lh0  = lds;                    // h0[p-1], rows r0..r0+31 (swizzled)
  float* lh1  = lds + LH_ELEMS;         // h1[p-2] (swizzled)
  float* zred = lds + 2 * LH_ELEMS;     // [2][32][33]
  float* mlpb = zred + ZRED_ELEMS;      // [4 waves][20]

  // ---- load weights ONCE, register-stationary for all 258 phases (96 VGPRs) ----
  float4 wx1w[8], wh1w[8], wh0w[8];
#pragma unroll
  for (int j = 0; j < 8; ++j) {
    wx1w[j] = *(const float4*)&A.Wx1[(size_t)(kb + j) * G4 + gq];
    wh1w[j] = *(const float4*)&A.Wh1[(size_t)(kb + j) * G4 + gq];
    wh0w[j] = *(const float4*)&A.Wh0[(size_t)(kb + j) * G4 + gq];
  }

  // per-thread cell constants (tid < 256 only)
  float b0g[4], b1g[4], wx0a[4], wx0b[4];
  if (tid < 256) {
#pragma unroll
    for (int g = 0; g < 4; ++g) {
      int gc = g * Hdim + c0 + hcc;
      b0g[g]  = A.b0[gc];
      b1g[g]  = A.b1[gc];
      wx0a[g] = A.Wx0[gc];        // one-hot row 0 (x = -1)
      wx0b[g] = A.Wx0[G4 + gc];   // one-hot row 1 (x = +1)
    }
  }
  float c0s = 0.f, c1s = 0.f;

  const bool hi5 = (lane & 32) != 0;
  const bool hi4 = (lane & 16) != 0;
  const bool hi3 = (lane & 8)  != 0;
  const int  lyz  = hi5 ? 1 : 0;                      // 0 -> z1 block, 1 -> z0 block
  const int  cloc = (hi4 ? 2 : 0) + (hi3 ? 1 : 0);
  const int  zwidx = (lyz * RB) * 33 + q * 4 + cloc;  // + r*33 at write time

  for (int p = 0; p <= Lseq + 1; ++p) {
    // ---------- stage h0[p-1], h1[p-2]: sc1 u64 loads -> regs -> LDS (swizzled) ----------
    const unsigned long long* h0src8 =
      (const unsigned long long*)(A.H0 + (size_t)((p + 1) & 1) * (Bsz * Hdim) + (size_t)r0 * Hdim);
    const unsigned long long* h1src8 =
      (const unsigned long long*)(A.H1 + (size_t)(p & 1) * (Bsz * Hdim) + (size_t)r0 * Hdim);
    {
      unsigned long long v[16];
#pragma unroll
      for (int it = 0; it < 16; ++it) {
        int e = it * NT + tid;                  // 0..8191 (32 rows x 256 8B-chunks)
        v[it] = __hip_atomic_load(&h0src8[(e >> 8) * 256 + (e & 255)],
                                  __ATOMIC_RELAXED, __HIP_MEMORY_SCOPE_AGENT);
      }
#pragma unroll
      for (int it = 0; it < 16; ++it) {
        int e = it * NT + tid;
        int d = (e & 255) * 2;                  // linear dword in row (even)
        *(unsigned long long*)&lh0[(e >> 8) * LHP + SWZ(d)] = v[it];
      }
#pragma unroll
      for (int it = 0; it < 16; ++it) {
        int e = it * NT + tid;
        v[it] = __hip_atomic_load(&h1src8[(e >> 8) * 256 + (e & 255)],
                                  __ATOMIC_RELAXED, __HIP_MEMORY_SCOPE_AGENT);
      }
#pragma unroll
      for (int it = 0; it < 16; ++it) {
        int e = it * NT + tid;
        int d = (e & 255) * 2;
        *(unsigned long long*)&lh1[(e >> 8) * LHP + SWZ(d)] = v[it];
      }
    }
    __syncthreads();                          // sync A

    const bool doL1  = (p >= 1 && p <= Lseq);
    const bool doL0  = (p < Lseq);
    const bool doMLP = (p >= 2 && cs < 32 && tid < 256);

    float xv = 0.f;
    if (tid < 256 && p < Lseq) xv = A.x[(r0 + rr2) * Lseq + p];

    // ---------- GEMM: weights in registers; swizzled conflict-free LDS reads ----------
#pragma unroll 2
    for (int r = 0; r < 32; ++r) {
      const float* lr0 = &lh0[r * LHP + koff];
      const float* lr1 = &lh1[r * LHP + koff];
      float4 ha = *(const float4*)lr0;
      float4 hb = *(const float4*)(lr0 + 4);
      float4 ga = *(const float4*)lr1;
      float4 gb = *(const float4*)(lr1 + 4);
      float h0v[8] = {ha.x, ha.y, ha.z, ha.w, hb.x, hb.y, hb.z, hb.w};
      float h1v[8] = {ga.x, ga.y, ga.z, ga.w, gb.x, gb.y, gb.z, gb.w};
      float hrv[8];
#pragma unroll
      for (int j = 0; j < 8; ++j) hrv[j] = fmaxf(h0v[j], 0.f);

      float4 az1 = {0.f, 0.f, 0.f, 0.f};
      float4 az0 = {0.f, 0.f, 0.f, 0.f};
#pragma unroll
      for (int j = 0; j < 8; ++j) {
        az1.x += hrv[j] * wx1w[j].x + h1v[j] * wh1w[j].x;
        az1.y += hrv[j] * wx1w[j].y + h1v[j] * wh1w[j].y;
        az1.z += hrv[j] * wx1w[j].z + h1v[j] * wh1w[j].z;
        az1.w += hrv[j] * wx1w[j].w + h1v[j] * wh1w[j].w;
        az0.x += h0v[j] * wh0w[j].x;
        az0.y += h0v[j] * wh0w[j].y;
        az0.z += h0v[j] * wh0w[j].z;
        az0.w += h0v[j] * wh0w[j].w;
      }

      // ---- reduce-scatter butterfly, ALL shuffles lane-uniform ----
      float s0x = hi5 ? az1.x : az0.x;
      float s0y = hi5 ? az1.y : az0.y;
      float s0z = hi5 ? az1.z : az0.z;
      float s0w = hi5 ? az1.w : az0.w;
      float v0 = (hi5 ? az0.x : az1.x) + __shfl_xor(s0x, 32);
      float v1 = (hi5 ? az0.y : az1.y) + __shfl_xor(s0y, 32);
      float v2 = (hi5 ? az0.z : az1.z) + __shfl_xor(s0z, 32);
      float v3 = (hi5 ? az0.w : az1.w) + __shfl_xor(s0w, 32);
      float sendA = hi4 ? v0 : v2;
      float u0 = (hi4 ? v2 : v0) + __shfl_xor(sendA, 16);
      float sendB = hi4 ? v1 : v3;
      float u1 = (hi4 ? v3 : v1) + __shfl_xor(sendB, 16);
      float sendC = hi3 ? u0 : u1;
      float t = (hi3 ? u1 : u0) + __shfl_xor(sendC, 8);
      t += __shfl_xor(t, 4);
      t += __shfl_xor(t, 2);
      t += __shfl_xor(t, 1);
      if ((lane & 7) == 0) zred[zwidx + r * 33] = t;
    }

    // ---------- MLP partials (waves 0-3; reads only lh1, swizzled) ----------
    if (doMLP) {
      float pr[10], pi[10];
#pragma unroll
      for (int j = 0; j < 10; ++j) { pr[j] = 0.f; pi[j] = 0.f; }
#pragma unroll
      for (int i2 = 0; i2 < 2; ++i2) {
        int k = (wv << 7) + (i2 << 6) + lane;
        float hv = fmaxf(lh1[cs * LHP + SWZ(k)], 0.f);
#pragma unroll
        for (int j = 0; j < 10; ++j) {
          pr[j] += hv * A.Wr1[k * 10 + j];
          pi[j] += hv * A.Wi1[k * 10 + j];
        }
      }
#pragma unroll
      for (int j = 0; j < 10; ++j)
#pragma unroll
        for (int off = 32; off >= 1; off >>= 1) {
          pr[j] += __shfl_xor(pr[j], off);
          pi[j] += __shfl_xor(pi[j], off);
        }
      if ((tid & 63) == 0) {
#pragma unroll
        for (int j = 0; j < 10; ++j) { mlpb[wv * 20 + j] = pr[j]; mlpb[wv * 20 + 10 + j] = pi[j]; }
      }
    }
    __syncthreads();                          // sync B

    // ---------- cell updates (tid < 256) ----------
    if (tid < 256) {
      if (doL1) {
        float z[4];
#pragma unroll
        for (int g = 0; g < 4; ++g)
          z[g] = zred[(0 * RB + rr2) * 33 + g * 8 + hcc] + b1g[g];
        float ig = sigf(z[0]), fg = sigf(z[1]), gg = tanhf(z[2]), og = sigf(z[3]);
        c1s = fg * c1s + ig * gg;
        float hv = og * tanhf(c1s);
        float* H1w = A.H1 + (size_t)((p + 1) & 1) * (Bsz * Hdim);
        __hip_atomic_store(&H1w[(r0 + rr2) * Hdim + c0 + hcc], hv,
                           __ATOMIC_RELAXED, __HIP_MEMORY_SCOPE_AGENT);
      }
      if (doL0) {
        float z[4];
#pragma unroll
        for (int g = 0; g < 4; ++g)
          z[g] = zred[(1 * RB + rr2) * 33 + g * 8 + hcc]
               + b0g[g] + (xv > 0.f ? wx0b[g] : wx0a[g]);
        float ig = sigf(z[0]), fg = sigf(z[1]), gg = tanhf(z[2]), og = sigf(z[3]);
        c0s = fg * c0s + ig * gg;
        float hv = og * tanhf(c0s);
        float* H0w = A.H0 + (size_t)(p & 1) * (Bsz * Hdim);
        __hip_atomic_store(&H0w[(r0 + rr2) * Hdim + c0 + hcc], hv,
                           __ATOMIC_RELAXED, __HIP_MEMORY_SCOPE_AGENT);
      }
    }

    // ---------- MLP epilogue + output (f32 PLANAR re|im) ----------
    if (doMLP && tid == 0) {
      const int t2 = p - 2, b = r0 + cs;
      float rsum[2] = {A.br2[0], A.br2[1]};
      float isum[2] = {A.bi2[0], A.bi2[1]};
#pragma unroll
      for (int j = 0; j < 10; ++j) {
        float ar = mlpb[j] + mlpb[20 + j] + mlpb[40 + j] + mlpb[60 + j] + A.br1[j];
        ar = fmaxf(ar, 0.f);
        rsum[0] += ar * A.Wr2[j * 2];
        rsum[1] += ar * A.Wr2[j * 2 + 1];
        float ai = mlpb[10 + j] + mlpb[30 + j] + mlpb[50 + j] + mlpb[70 + j] + A.bi1[j];
        ai = fmaxf(ai, 0.f);
        isum[0] += ai * A.Wi2[j * 2];
        isum[1] += ai * A.Wi2[j * 2 + 1];
      }
#pragma unroll
      for (int m = 0; m < 2; ++m) {
        float im = 3.14159265358979323846f * (isum[m] / (1.f + fabsf(isum[m])));
        float sv, cv;
        sincosf(im, &sv, &cv);
        const int c = (b * Lseq + t2) * 2 + m;
        A.out[c]           = rsum[m] * cv;   // real
        A.out[OUTHALF + c] = rsum[m] * sv;   // imag
      }
    }

    // ---------- grid barrier: 8 monotonic counters, 8 pollers per wg ----------
    __syncthreads();
    if (tid == 0) {
      __hip_atomic_fetch_add(&A.cnt[w & 7], 1, __ATOMIC_RELEASE, __HIP_MEMORY_SCOPE_AGENT);
    }
    if (tid < 8) {
      const int target = (p + 1) * (NWG / 8);
      while (__hip_atomic_load(&A.cnt[tid], __ATOMIC_ACQUIRE, __HIP_MEMORY_SCOPE_AGENT) < target) {
        __builtin_amdgcn_s_sleep(2);
      }
    }
    __syncthreads();
  }
}

extern "C" void kernel_launch(void* const* d_in, const int* in_sizes, int n_in,
                              void* d_out, int out_size, void* d_ws, size_t ws_size,
                              hipStream_t stream) {
  const float* P[15];
  for (int i = 0; i < 15; ++i) P[i] = (const float*)d_in[i];
  if (in_sizes[0] != Bsz * Lseq) {
    static const int m_[15] = {14, 6, 0, 8, 7, 1, 9, 4, 12, 5, 13, 2, 10, 3, 11};
    for (int i = 0; i < 15; ++i) P[i] = (const float*)d_in[m_[i]];
  }

  PArgs a;
  a.x   = P[0];
  a.Wx0 = P[1];
  a.Wh0 = P[2];
  a.b0  = P[3];
  a.Wx1 = P[4];
  a.Wh1 = P[5];
  a.b1  = P[6];
  a.Wr1 = P[7];
  a.br1 = P[8];
  a.Wr2 = P[9];
  a.br2 = P[10];
  a.Wi1 = P[11];
  a.bi1 = P[12];
  a.Wi2 = P[13];
  a.bi2 = P[14];

  float* ws = (float*)d_ws;
  a.H0 = ws;
  a.H1 = ws + 2 * Bsz * Hdim;
  a.cnt = (int*)(ws + 4 * Bsz * Hdim);
  a.out = (float*)d_out;

  // zero H state (both parities) + counters every call (replay-safe)
  hipMemsetAsync(ws, 0, (size_t)(4 * Bsz * Hdim) * sizeof(float) + NWG * sizeof(int), stream);

  hipFuncSetAttribute((const void*)lstm_persist,
                      hipFuncAttributeMaxDynamicSharedMemorySize, LDS_BYTES);
  lstm_persist<<<dim3(NWG), dim3(NT), LDS_BYTES, stream>>>(a);
}

// Round 17
// 6177.703 us; speedup vs baseline: 1.4002x; 1.4002x over previous
//
#include <hip/hip_runtime.h>
#include <math.h>

#define Bsz  128
#define Lseq 256
#define Hdim 512
#define G4   2048
#define NWG  256
#define NT   512
#define RB   32
#define LHS  520    // bf16 plane row stride (shorts): 1040 B = 16 mod 128 -> 4-bank row shift, conflict-free b128 frag reads
#define OUTHALF (Bsz * Lseq * 2)

typedef __attribute__((ext_vector_type(8))) short s8v;   // 8 bf16 = 4 VGPR (MFMA A/B frag)
typedef __attribute__((ext_vector_type(4))) float f4v;   // MFMA C/D frag
typedef unsigned long long u64;
typedef unsigned int u32;
typedef unsigned short u16;

#define PLANE_SH (RB * LHS)        // 16640 shorts per plane
#define ZR_F     4096              // floats per zr array: [kg2][mt2][nt2][lane64][reg4]
#define MLP_F    80
#define LDS_BYTES (3 * PLANE_SH * 2 + (2 * ZR_F + MLP_F) * 4)   // 132,928 B < 160 KiB

struct PArgs {
  const float *x, *Wx0, *Wh0, *b0, *Wx1, *Wh1, *b1;
  const float *Wr1, *br1, *Wr2, *br2, *Wi1, *bi1, *Wi2, *bi2;
  u16  *H0, *H1;                   // bf16 double-buffered [2][128][512]
  int  *cnt;                       // 4 per-batch-group barrier counters (monotonic)
  float *out;                      // f32 PLANAR: [re (B,L,2)][im (B,L,2)]
};

__device__ __forceinline__ float sigf(float z) { return 1.f / (1.f + expf(-z)); }
__device__ __forceinline__ u16 f2bf(float f) {
  u32 u = __float_as_uint(f);
  return (u16)((u + 0x7FFFu + ((u >> 16) & 1u)) >> 16);
}
__device__ __forceinline__ float bf2f(u16 h) { return __uint_as_float(((u32)h) << 16); }
__device__ __forceinline__ u32 relu2(u32 x) {          // relu on 2 packed bf16
  u32 m = ((x & 0x80008000u) >> 15) * 0xFFFFu;
  return x & ~m;
}

__global__ void __launch_bounds__(NT, 1) lstm_persist(PArgs A) {
  const int w    = blockIdx.x;
  const int tid  = threadIdx.x;
  const int cs   = (w & 7) * 8 + ((w >> 3) & 7);  // XCD-contiguous col slices
  const int bg   = w >> 6;                         // batch group 0..3
  const int r0   = bg * RB;
  const int c0   = cs * 8;
  // MFMA wave mapping: wave = (mt, nt, kg)
  const int wq   = tid >> 6;
  const int lane = tid & 63;
  const int mt   = wq & 1;
  const int nt2  = (wq >> 1) & 1;
  const int kg   = wq >> 2;             // K-half 0/1 (256 each)
  const int lhi  = lane >> 4;           // 0..3
  const int llo  = lane & 15;
  // cell mapping (tid < 256)
  const int rr2  = (tid >> 3) & 31;
  const int hcc  = tid & 7;
  // MLP mapping (tid < 256)
  const int wv   = (tid >> 6) & 3;

  extern __shared__ char smem[];
  short* lh0s  = (short*)smem;               // h0[p-1] bf16
  short* lh0rs = lh0s + PLANE_SH;            // relu(h0[p-1]) bf16
  short* lh1s  = lh0rs + PLANE_SH;           // h1[p-2] bf16
  float* zr1   = (float*)(lh1s + PLANE_SH);  // z1 partials
  float* zr0   = zr1 + ZR_F;                 // z0 partials
  float* mlpb  = zr0 + ZR_F;

  // ---- one-time: B fragments (bf16) register-stationary. Same (lhi,j)->k ----
  // ---- bijection as the A reads => k-permutation-immune (see analysis).   ----
  const int nloc = nt2 * 16 + llo;                       // local col 0..31
  const int gcol = (nloc >> 3) * Hdim + c0 + (nloc & 7); // global gate-col
  s8v bx1f[8], bh1f[8], bh0f[8];
#pragma unroll
  for (int s = 0; s < 8; ++s) {
    const int kbase = kg * 256 + s * 32 + lhi * 8;
#pragma unroll
    for (int j = 0; j < 8; ++j) {
      const int k = kbase + j;
      bx1f[s][j] = (short)f2bf(A.Wx1[(size_t)k * G4 + gcol]);
      bh1f[s][j] = (short)f2bf(A.Wh1[(size_t)k * G4 + gcol]);
      bh0f[s][j] = (short)f2bf(A.Wh0[(size_t)k * G4 + gcol]);
    }
  }

  // per-thread cell constants (tid < 256 only)
  float b0g[4], b1g[4], wx0a[4], wx0b[4];
  if (tid < 256) {
#pragma unroll
    for (int g = 0; g < 4; ++g) {
      int gc = g * Hdim + c0 + hcc;
      b0g[g]  = A.b0[gc];
      b1g[g]  = A.b1[gc];
      wx0a[g] = A.Wx0[gc];
      wx0b[g] = A.Wx0[G4 + gc];
    }
  }
  float c0s = 0.f, c1s = 0.f;

  for (int p = 0; p <= Lseq + 1; ++p) {
    // ---------- stage h0[p-1], h1[p-2] (bf16, sc1 u64) -> LDS planes ----------
    const u64* h0g = (const u64*)(A.H0 + (size_t)((p + 1) & 1) * (Bsz * Hdim)) + (size_t)r0 * 128;
    const u64* h1g = (const u64*)(A.H1 + (size_t)(p & 1) * (Bsz * Hdim)) + (size_t)r0 * 128;
#pragma unroll
    for (int it = 0; it < 8; ++it) {
      int e = it * NT + tid;                 // 0..4095 (32 rows x 128 u64)
      int row = e >> 7, c4 = e & 127;
      u64 v = __hip_atomic_load(&h0g[row * 128 + c4], __ATOMIC_RELAXED, __HIP_MEMORY_SCOPE_AGENT);
      *(u64*)&lh0s[row * LHS + c4 * 4] = v;
      u32 lo = relu2((u32)v), hi = relu2((u32)(v >> 32));
      *(u64*)&lh0rs[row * LHS + c4 * 4] = ((u64)hi << 32) | lo;
    }
#pragma unroll
    for (int it = 0; it < 8; ++it) {
      int e = it * NT + tid;
      int row = e >> 7, c4 = e & 127;
      u64 v = __hip_atomic_load(&h1g[row * 128 + c4], __ATOMIC_RELAXED, __HIP_MEMORY_SCOPE_AGENT);
      *(u64*)&lh1s[row * LHS + c4 * 4] = v;
    }
    __syncthreads();                          // sync A

    const bool doL1  = (p >= 1 && p <= Lseq);
    const bool doL0  = (p < Lseq);
    const bool doMLP = (p >= 2 && cs < 32 && tid < 256);

    float xv = 0.f;
    if (tid < 256 && p < Lseq) xv = A.x[(r0 + rr2) * Lseq + p];

    // ---------- MFMA GEMM: z1 = relu(h0)@Wx1 + h1@Wh1 ; z0 = h0@Wh0 ----------
    {
      f4v c1 = {0.f, 0.f, 0.f, 0.f};
      f4v cz = {0.f, 0.f, 0.f, 0.f};
      const int abase = (mt * 16 + llo) * LHS + kg * 256 + lhi * 8;
#pragma unroll
      for (int s = 0; s < 8; ++s) {
        const int ao = abase + s * 32;
        s8v ar = *(const s8v*)&lh0rs[ao];
        s8v a1 = *(const s8v*)&lh1s[ao];
        s8v a0 = *(const s8v*)&lh0s[ao];
        c1 = __builtin_amdgcn_mfma_f32_16x16x32_bf16(ar, bx1f[s], c1, 0, 0, 0);
        c1 = __builtin_amdgcn_mfma_f32_16x16x32_bf16(a1, bh1f[s], c1, 0, 0, 0);
        cz = __builtin_amdgcn_mfma_f32_16x16x32_bf16(a0, bh0f[s], cz, 0, 0, 0);
      }
      const int zi = (((kg * 2 + mt) * 2 + nt2) * 64 + lane) * 4;
      *(f4v*)&zr1[zi] = c1;
      *(f4v*)&zr0[zi] = cz;
    }

    // ---------- MLP partials (waves 0-3; reads lh1 bf16) ----------
    if (doMLP) {
      float pr[10], pi[10];
#pragma unroll
      for (int j = 0; j < 10; ++j) { pr[j] = 0.f; pi[j] = 0.f; }
#pragma unroll
      for (int i2 = 0; i2 < 2; ++i2) {
        int k = (wv << 7) + (i2 << 6) + (tid & 63);
        float hv = fmaxf(bf2f((u16)lh1s[cs * LHS + k]), 0.f);
#pragma unroll
        for (int j = 0; j < 10; ++j) {
          pr[j] += hv * A.Wr1[k * 10 + j];
          pi[j] += hv * A.Wi1[k * 10 + j];
        }
      }
#pragma unroll
      for (int j = 0; j < 10; ++j)
#pragma unroll
        for (int off = 32; off >= 1; off >>= 1) {
          pr[j] += __shfl_xor(pr[j], off);
          pi[j] += __shfl_xor(pi[j], off);
        }
      if ((tid & 63) == 0) {
#pragma unroll
        for (int j = 0; j < 10; ++j) { mlpb[wv * 20 + j] = pr[j]; mlpb[wv * 20 + 10 + j] = pi[j]; }
      }
    }
    __syncthreads();                          // sync B

    // ---------- cell updates (tid < 256): unmap C/D frags, gate math ----------
    if (tid < 256) {
      const int mtl  = rr2 >> 4;
      const int rt   = rr2 & 15;
      const int reg  = rt & 3;
      if (doL1) {
        float z[4];
#pragma unroll
        for (int g = 0; g < 4; ++g) {
          int n = g * 8 + hcc, ntl = n >> 4, cit = n & 15;
          int lane_ = ((rt >> 2) << 4) | cit;
          z[g] = zr1[(((0 * 2 + mtl) * 2 + ntl) * 64 + lane_) * 4 + reg]
               + zr1[(((1 * 2 + mtl) * 2 + ntl) * 64 + lane_) * 4 + reg] + b1g[g];
        }
        float ig = sigf(z[0]), fg = sigf(z[1]), gg = tanhf(z[2]), og = sigf(z[3]);
        c1s = fg * c1s + ig * gg;
        float hv = og * tanhf(c1s);
        u16* H1w = A.H1 + (size_t)((p + 1) & 1) * (Bsz * Hdim);
        H1w[(r0 + rr2) * Hdim + c0 + hcc] = f2bf(hv);
      }
      if (doL0) {
        float z[4];
#pragma unroll
        for (int g = 0; g < 4; ++g) {
          int n = g * 8 + hcc, ntl = n >> 4, cit = n & 15;
          int lane_ = ((rt >> 2) << 4) | cit;
          z[g] = zr0[(((0 * 2 + mtl) * 2 + ntl) * 64 + lane_) * 4 + reg]
               + zr0[(((1 * 2 + mtl) * 2 + ntl) * 64 + lane_) * 4 + reg]
               + b0g[g] + (xv > 0.f ? wx0b[g] : wx0a[g]);
        }
        float ig = sigf(z[0]), fg = sigf(z[1]), gg = tanhf(z[2]), og = sigf(z[3]);
        c0s = fg * c0s + ig * gg;
        float hv = og * tanhf(c0s);
        u16* H0w = A.H0 + (size_t)(p & 1) * (Bsz * Hdim);
        H0w[(r0 + rr2) * Hdim + c0 + hcc] = f2bf(hv);
      }
    }

    // ---------- MLP epilogue + output (f32 PLANAR re|im) ----------
    if (doMLP && tid == 0) {
      const int t2 = p - 2, b = r0 + cs;
      float rsum[2] = {A.br2[0], A.br2[1]};
      float isum[2] = {A.bi2[0], A.bi2[1]};
#pragma unroll
      for (int j = 0; j < 10; ++j) {
        float ar = mlpb[j] + mlpb[20 + j] + mlpb[40 + j] + mlpb[60 + j] + A.br1[j];
        ar = fmaxf(ar, 0.f);
        rsum[0] += ar * A.Wr2[j * 2];
        rsum[1] += ar * A.Wr2[j * 2 + 1];
        float ai = mlpb[10 + j] + mlpb[30 + j] + mlpb[50 + j] + mlpb[70 + j] + A.bi1[j];
        ai = fmaxf(ai, 0.f);
        isum[0] += ai * A.Wi2[j * 2];
        isum[1] += ai * A.Wi2[j * 2 + 1];
      }
#pragma unroll
      for (int m = 0; m < 2; ++m) {
        float im = 3.14159265358979323846f * (isum[m] / (1.f + fabsf(isum[m])));
        float sv, cv;
        sincosf(im, &sv, &cv);
        const int c = (b * Lseq + t2) * 2 + m;
        A.out[c]           = rsum[m] * cv;
        A.out[OUTHALF + c] = rsum[m] * sv;
      }
    }

    // ---------- per-batch-group barrier (64 wgs; RELEASE flushes h stores) ----------
    __syncthreads();
    if (tid == 0) {
      __hip_atomic_fetch_add(&A.cnt[bg], 1, __ATOMIC_RELEASE, __HIP_MEMORY_SCOPE_AGENT);
      const int target = (p + 1) * 64;
      while (__hip_atomic_load(&A.cnt[bg], __ATOMIC_ACQUIRE, __HIP_MEMORY_SCOPE_AGENT) < target) {
        __builtin_amdgcn_s_sleep(2);
      }
    }
    __syncthreads();
  }
}

extern "C" void kernel_launch(void* const* d_in, const int* in_sizes, int n_in,
                              void* d_out, int out_size, void* d_ws, size_t ws_size,
                              hipStream_t stream) {
  const float* P[15];
  for (int i = 0; i < 15; ++i) P[i] = (const float*)d_in[i];
  if (in_sizes[0] != Bsz * Lseq) {
    static const int m_[15] = {14, 6, 0, 8, 7, 1, 9, 4, 12, 5, 13, 2, 10, 3, 11};
    for (int i = 0; i < 15; ++i) P[i] = (const float*)d_in[m_[i]];
  }

  PArgs a;
  a.x   = P[0];
  a.Wx0 = P[1];
  a.Wh0 = P[2];
  a.b0  = P[3];
  a.Wx1 = P[4];
  a.Wh1 = P[5];
  a.b1  = P[6];
  a.Wr1 = P[7];
  a.br1 = P[8];
  a.Wr2 = P[9];
  a.br2 = P[10];
  a.Wi1 = P[11];
  a.bi1 = P[12];
  a.Wi2 = P[13];
  a.bi2 = P[14];

  // workspace: H0/H1 bf16 [2][128][512] each + counters
  u16* H0 = (u16*)d_ws;
  a.H0 = H0;
  a.H1 = H0 + (size_t)2 * Bsz * Hdim;
  a.cnt = (int*)(H0 + (size_t)4 * Bsz * Hdim);
  a.out = (float*)d_out;

  // zero H (both parities, both layers) + counters every call (replay-safe)
  hipMemsetAsync(d_ws, 0, (size_t)4 * Bsz * Hdim * sizeof(u16) + NWG * sizeof(int), stream);

  hipFuncSetAttribute((const void*)lstm_persist,
                      hipFuncAttributeMaxDynamicSharedMemorySize, LDS_BYTES);
  lstm_persist<<<dim3(NWG), dim3(NT), LDS_BYTES, stream>>>(a);
}

// Round 18
// 5905.967 us; speedup vs baseline: 1.4647x; 1.0460x over previous
//
#include <hip/hip_runtime.h>
#include <math.h>

#define Bsz  128
#define Lseq 256
#define Hdim 512
#define G4   2048
#define NWG  256
#define NT   512
#define RB   32
#define LHS  520    // bf16 plane row stride (shorts): 1040 B = 16 mod 128 -> 4-bank row shift, conflict-free b128 frag reads
#define OUTHALF (Bsz * Lseq * 2)

typedef __attribute__((ext_vector_type(8))) short s8v;   // 8 bf16 = 4 VGPR (MFMA A/B frag)
typedef __attribute__((ext_vector_type(4))) float f4v;   // MFMA C/D frag
typedef unsigned long long u64;
typedef unsigned int u32;
typedef unsigned short u16;

#define PLANE_SH (RB * LHS)        // 16640 shorts per plane
#define ZR_F     4096              // floats per zr array: [kg2][mt2][nt2][lane64][reg4]
#define MLP_F    80
#define LDS_BYTES (3 * PLANE_SH * 2 + (2 * ZR_F + MLP_F) * 4)   // 132,928 B < 160 KiB

struct PArgs {
  const float *x, *Wx0, *Wh0, *b0, *Wx1, *Wh1, *b1;
  const float *Wr1, *br1, *Wr2, *br2, *Wi1, *bi1, *Wi2, *bi2;
  u16  *H0, *H1;                   // bf16 double-buffered [2][128][512]
  int  *cnt;                       // 4 per-batch-group barrier counters (monotonic)
  float *out;                      // f32 PLANAR: [re (B,L,2)][im (B,L,2)]
};

__device__ __forceinline__ float sigf(float z) { return 1.f / (1.f + expf(-z)); }
__device__ __forceinline__ u16 f2bf(float f) {
  u32 u = __float_as_uint(f);
  return (u16)((u + 0x7FFFu + ((u >> 16) & 1u)) >> 16);
}
__device__ __forceinline__ float bf2f(u16 h) { return __uint_as_float(((u32)h) << 16); }
__device__ __forceinline__ u32 relu2(u32 x) {          // relu on 2 packed bf16
  u32 m = ((x & 0x80008000u) >> 15) * 0xFFFFu;
  return x & ~m;
}

__global__ void __launch_bounds__(NT, 1) lstm_persist(PArgs A) {
  const int w    = blockIdx.x;
  const int tid  = threadIdx.x;
  const int cs   = (w & 7) * 8 + ((w >> 3) & 7);  // XCD-contiguous col slices
  const int bg   = w >> 6;                         // batch group 0..3
  const int r0   = bg * RB;
  const int c0   = cs * 8;
  // MFMA wave mapping: wave = (mt, nt, kg)
  const int wq   = tid >> 6;
  const int lane = tid & 63;
  const int mt   = wq & 1;
  const int nt2  = (wq >> 1) & 1;
  const int kg   = wq >> 2;             // K-half 0/1 (256 each)
  const int lhi  = lane >> 4;           // 0..3
  const int llo  = lane & 15;
  // cell mapping (tid < 256)
  const int rr2  = (tid >> 3) & 31;
  const int hcc  = tid & 7;
  // MLP mapping (tid < 256)
  const int wv   = (tid >> 6) & 3;

  extern __shared__ char smem[];
  short* lh0s  = (short*)smem;               // h0[p-1] bf16
  short* lh0rs = lh0s + PLANE_SH;            // relu(h0[p-1]) bf16
  short* lh1s  = lh0rs + PLANE_SH;           // h1[p-2] bf16
  float* zr1   = (float*)(lh1s + PLANE_SH);  // z1 partials
  float* zr0   = zr1 + ZR_F;                 // z0 partials
  float* mlpb  = zr0 + ZR_F;

  // ---- one-time: B fragments (bf16) register-stationary. Same (lhi,j)->k ----
  // ---- bijection as the A reads => k-permutation-immune (see analysis).   ----
  const int nloc = nt2 * 16 + llo;                       // local col 0..31
  const int gcol = (nloc >> 3) * Hdim + c0 + (nloc & 7); // global gate-col
  s8v bx1f[8], bh1f[8], bh0f[8];
#pragma unroll
  for (int s = 0; s < 8; ++s) {
    const int kbase = kg * 256 + s * 32 + lhi * 8;
#pragma unroll
    for (int j = 0; j < 8; ++j) {
      const int k = kbase + j;
      bx1f[s][j] = (short)f2bf(A.Wx1[(size_t)k * G4 + gcol]);
      bh1f[s][j] = (short)f2bf(A.Wh1[(size_t)k * G4 + gcol]);
      bh0f[s][j] = (short)f2bf(A.Wh0[(size_t)k * G4 + gcol]);
    }
  }

  // per-thread cell constants (tid < 256 only)
  float b0g[4], b1g[4], wx0a[4], wx0b[4];
  if (tid < 256) {
#pragma unroll
    for (int g = 0; g < 4; ++g) {
      int gc = g * Hdim + c0 + hcc;
      b0g[g]  = A.b0[gc];
      b1g[g]  = A.b1[gc];
      wx0a[g] = A.Wx0[gc];
      wx0b[g] = A.Wx0[G4 + gc];
    }
  }
  float c0s = 0.f, c1s = 0.f;

  for (int p = 0; p <= Lseq + 1; ++p) {
    // ---------- stage h0[p-1], h1[p-2] (bf16, sc1 u64) -> LDS planes ----------
    const u64* h0g = (const u64*)(A.H0 + (size_t)((p + 1) & 1) * (Bsz * Hdim)) + (size_t)r0 * 128;
    const u64* h1g = (const u64*)(A.H1 + (size_t)(p & 1) * (Bsz * Hdim)) + (size_t)r0 * 128;
#pragma unroll
    for (int it = 0; it < 8; ++it) {
      int e = it * NT + tid;                 // 0..4095 (32 rows x 128 u64)
      int row = e >> 7, c4 = e & 127;
      u64 v = __hip_atomic_load(&h0g[row * 128 + c4], __ATOMIC_RELAXED, __HIP_MEMORY_SCOPE_AGENT);
      *(u64*)&lh0s[row * LHS + c4 * 4] = v;
      u32 lo = relu2((u32)v), hi = relu2((u32)(v >> 32));
      *(u64*)&lh0rs[row * LHS + c4 * 4] = ((u64)hi << 32) | lo;
    }
#pragma unroll
    for (int it = 0; it < 8; ++it) {
      int e = it * NT + tid;
      int row = e >> 7, c4 = e & 127;
      u64 v = __hip_atomic_load(&h1g[row * 128 + c4], __ATOMIC_RELAXED, __HIP_MEMORY_SCOPE_AGENT);
      *(u64*)&lh1s[row * LHS + c4 * 4] = v;
    }
    __syncthreads();                          // sync A

    const bool doL1  = (p >= 1 && p <= Lseq);
    const bool doL0  = (p < Lseq);
    const bool doMLP = (p >= 2 && cs < 32 && tid < 256);

    float xv = 0.f;
    if (tid < 256 && p < Lseq) xv = A.x[(r0 + rr2) * Lseq + p];

    // ---------- MFMA GEMM: z1 = relu(h0)@Wx1 + h1@Wh1 ; z0 = h0@Wh0 ----------
    {
      f4v c1 = {0.f, 0.f, 0.f, 0.f};
      f4v cz = {0.f, 0.f, 0.f, 0.f};
      const int abase = (mt * 16 + llo) * LHS + kg * 256 + lhi * 8;
#pragma unroll
      for (int s = 0; s < 8; ++s) {
        const int ao = abase + s * 32;
        s8v ar = *(const s8v*)&lh0rs[ao];
        s8v a1 = *(const s8v*)&lh1s[ao];
        s8v a0 = *(const s8v*)&lh0s[ao];
        c1 = __builtin_amdgcn_mfma_f32_16x16x32_bf16(ar, bx1f[s], c1, 0, 0, 0);
        c1 = __builtin_amdgcn_mfma_f32_16x16x32_bf16(a1, bh1f[s], c1, 0, 0, 0);
        cz = __builtin_amdgcn_mfma_f32_16x16x32_bf16(a0, bh0f[s], cz, 0, 0, 0);
      }
      const int zi = (((kg * 2 + mt) * 2 + nt2) * 64 + lane) * 4;
      *(f4v*)&zr1[zi] = c1;
      *(f4v*)&zr0[zi] = cz;
    }

    // ---------- MLP partials (waves 0-3; reads lh1 bf16) ----------
    if (doMLP) {
      float pr[10], pi[10];
#pragma unroll
      for (int j = 0; j < 10; ++j) { pr[j] = 0.f; pi[j] = 0.f; }
#pragma unroll
      for (int i2 = 0; i2 < 2; ++i2) {
        int k = (wv << 7) + (i2 << 6) + (tid & 63);
        float hv = fmaxf(bf2f((u16)lh1s[cs * LHS + k]), 0.f);
#pragma unroll
        for (int j = 0; j < 10; ++j) {
          pr[j] += hv * A.Wr1[k * 10 + j];
          pi[j] += hv * A.Wi1[k * 10 + j];
        }
      }
#pragma unroll
      for (int j = 0; j < 10; ++j)
#pragma unroll
        for (int off = 32; off >= 1; off >>= 1) {
          pr[j] += __shfl_xor(pr[j], off);
          pi[j] += __shfl_xor(pi[j], off);
        }
      if ((tid & 63) == 0) {
#pragma unroll
        for (int j = 0; j < 10; ++j) { mlpb[wv * 20 + j] = pr[j]; mlpb[wv * 20 + 10 + j] = pi[j]; }
      }
    }
    __syncthreads();                          // sync B

    // ---------- cell updates (tid < 256): unmap C/D frags, gate math ----------
    if (tid < 256) {
      const int mtl  = rr2 >> 4;
      const int rt   = rr2 & 15;
      const int reg  = rt & 3;
      if (doL1) {
        float z[4];
#pragma unroll
        for (int g = 0; g < 4; ++g) {
          int n = g * 8 + hcc, ntl = n >> 4, cit = n & 15;
          int lane_ = ((rt >> 2) << 4) | cit;
          z[g] = zr1[(((0 * 2 + mtl) * 2 + ntl) * 64 + lane_) * 4 + reg]
               + zr1[(((1 * 2 + mtl) * 2 + ntl) * 64 + lane_) * 4 + reg] + b1g[g];
        }
        float ig = sigf(z[0]), fg = sigf(z[1]), gg = tanhf(z[2]), og = sigf(z[3]);
        c1s = fg * c1s + ig * gg;
        float hv = og * tanhf(c1s);
        u16* H1w = A.H1 + (size_t)((p + 1) & 1) * (Bsz * Hdim);
        H1w[(r0 + rr2) * Hdim + c0 + hcc] = f2bf(hv);
      }
      if (doL0) {
        float z[4];
#pragma unroll
        for (int g = 0; g < 4; ++g) {
          int n = g * 8 + hcc, ntl = n >> 4, cit = n & 15;
          int lane_ = ((rt >> 2) << 4) | cit;
          z[g] = zr0[(((0 * 2 + mtl) * 2 + ntl) * 64 + lane_) * 4 + reg]
               + zr0[(((1 * 2 + mtl) * 2 + ntl) * 64 + lane_) * 4 + reg]
               + b0g[g] + (xv > 0.f ? wx0b[g] : wx0a[g]);
        }
        float ig = sigf(z[0]), fg = sigf(z[1]), gg = tanhf(z[2]), og = sigf(z[3]);
        c0s = fg * c0s + ig * gg;
        float hv = og * tanhf(c0s);
        u16* H0w = A.H0 + (size_t)(p & 1) * (Bsz * Hdim);
        H0w[(r0 + rr2) * Hdim + c0 + hcc] = f2bf(hv);
      }
    }

    // ---------- MLP epilogue + output (f32 PLANAR re|im) ----------
    if (doMLP && tid == 0) {
      const int t2 = p - 2, b = r0 + cs;
      float rsum[2] = {A.br2[0], A.br2[1]};
      float isum[2] = {A.bi2[0], A.bi2[1]};
#pragma unroll
      for (int j = 0; j < 10; ++j) {
        float ar = mlpb[j] + mlpb[20 + j] + mlpb[40 + j] + mlpb[60 + j] + A.br1[j];
        ar = fmaxf(ar, 0.f);
        rsum[0] += ar * A.Wr2[j * 2];
        rsum[1] += ar * A.Wr2[j * 2 + 1];
        float ai = mlpb[10 + j] + mlpb[30 + j] + mlpb[50 + j] + mlpb[70 + j] + A.bi1[j];
        ai = fmaxf(ai, 0.f);
        isum[0] += ai * A.Wi2[j * 2];
        isum[1] += ai * A.Wi2[j * 2 + 1];
      }
#pragma unroll
      for (int m = 0; m < 2; ++m) {
        float im = 3.14159265358979323846f * (isum[m] / (1.f + fabsf(isum[m])));
        float sv, cv;
        sincosf(im, &sv, &cv);
        const int c = (b * Lseq + t2) * 2 + m;
        A.out[c]           = rsum[m] * cv;
        A.out[OUTHALF + c] = rsum[m] * sv;
      }
    }

    // ---------- per-batch-group barrier (64 wgs; RELEASE flushes h stores) ----------
    __syncthreads();
    if (tid == 0) {
      __hip_atomic_fetch_add(&A.cnt[bg], 1, __ATOMIC_RELEASE, __HIP_MEMORY_SCOPE_AGENT);
      const int target = (p + 1) * 64;
      while (__hip_atomic_load(&A.cnt[bg], __ATOMIC_ACQUIRE, __HIP_MEMORY_SCOPE_AGENT) < target) {
        __builtin_amdgcn_s_sleep(2);
      }
    }
    __syncthreads();
  }
}

extern "C" void kernel_launch(void* const* d_in, const int* in_sizes, int n_in,
                              void* d_out, int out_size, void* d_ws, size_t ws_size,
                              hipStream_t stream) {
  const float* P[15];
  for (int i = 0; i < 15; ++i) P[i] = (const float*)d_in[i];
  if (in_sizes[0] != Bsz * Lseq) {
    static const int m_[15] = {14, 6, 0, 8, 7, 1, 9, 4, 12, 5, 13, 2, 10, 3, 11};
    for (int i = 0; i < 15; ++i) P[i] = (const float*)d_in[m_[i]];
  }

  PArgs a;
  a.x   = P[0];
  a.Wx0 = P[1];
  a.Wh0 = P[2];
  a.b0  = P[3];
  a.Wx1 = P[4];
  a.Wh1 = P[5];
  a.b1  = P[6];
  a.Wr1 = P[7];
  a.br1 = P[8];
  a.Wr2 = P[9];
  a.br2 = P[10];
  a.Wi1 = P[11];
  a.bi1 = P[12];
  a.Wi2 = P[13];
  a.bi2 = P[14];

  // workspace: H0/H1 bf16 [2][128][512] each + counters
  u16* H0 = (u16*)d_ws;
  a.H0 = H0;
  a.H1 = H0 + (size_t)2 * Bsz * Hdim;
  a.cnt = (int*)(H0 + (size_t)4 * Bsz * Hdim);
  a.out = (float*)d_out;

  // zero H (both parities, both layers) + counters every call (replay-safe)
  hipMemsetAsync(d_ws, 0, (size_t)4 * Bsz * Hdim * sizeof(u16) + NWG * sizeof(int), stream);

  hipFuncSetAttribute((const void*)lstm_persist,
                      hipFuncAttributeMaxDynamicSharedMemorySize, LDS_BYTES);
  lstm_persist<<<dim3(NWG), dim3(NT), LDS_BYTES, stream>>>(a);
}